// Round 17
// baseline (264.680 us; speedup 1.0000x reference)
//
#include <hip/hip_runtime.h>
#include <math.h>

typedef __bf16 bf16x8 __attribute__((ext_vector_type(8)));
typedef _Float16 f16x8 __attribute__((ext_vector_type(8)));
typedef _Float16 f16x4 __attribute__((ext_vector_type(4)));
typedef float f32x4 __attribute__((ext_vector_type(4)));

__device__ __forceinline__ unsigned short f2bf(float f) {
  unsigned int u = __builtin_bit_cast(unsigned int, f);
  u += 0x7fffu + ((u >> 16) & 1u);
  return (unsigned short)(u >> 16);
}
__device__ __forceinline__ unsigned int pack2bf(float a, float b) {
  return (unsigned int)f2bf(a) | ((unsigned int)f2bf(b) << 16);
}

// ---------- fused: fp32->bf16 convert (W1L, W2L, x) + Whh fp16 prep ----------
__global__ __launch_bounds__(256) void convert_prep(
    const float* __restrict__ s0, const float* __restrict__ s1,
    const float* __restrict__ s2, unsigned short* __restrict__ d0,
    unsigned short* __restrict__ d1, unsigned short* __restrict__ d2,
    int n0, int n1, int n2,
    const float* __restrict__ Whh, _Float16* __restrict__ P) {
  const int b = blockIdx.x;
  if (b < 1536) {
    int i4 = (b * 256 + threadIdx.x) * 4;
    const float* s; unsigned short* d; int off;
    if (i4 < n0) { s = s0; d = d0; off = i4; }
    else if (i4 < n0 + n1) { s = s1; d = d1; off = i4 - n0; }
    else if (i4 < n0 + n1 + n2) { s = s2; d = d2; off = i4 - n0 - n1; }
    else return;
    float4 v = *(const float4*)&s[off];
    ushort4 o = { f2bf(v.x), f2bf(v.y), f2bf(v.z), f2bf(v.w) };
    *(ushort4*)&d[off] = o;
  } else {
    // prep: perm row 4*hid+gate = Whh[gate*100+hid][0:100], K-stride 128, pad 0
    const int idx = (b - 1536) * 256 + threadIdx.x;
    if (idx >= 400 * 16) return;
    const int row = idx >> 4, ch = idx & 15;
    const int hid = row >> 2, gate = row & 3;
    const int src = gate * 100 + hid;
    f16x8 v;
#pragma unroll
    for (int j = 0; j < 8; j++) {
      const int k = ch * 8 + j;
      float f = (k < 100) ? Whh[(size_t)src * 100 + k] : 0.f;
      v[j] = (_Float16)f;
    }
    *(f16x8*)&P[(size_t)row * 128 + ch * 8] = v;
  }
}

// ---------- bf16 MFMA GEMM + sigmoid + avgpool2 (R2-proven pure-bf16 path) ----------
#define GK_PADK 40
template <int WFP32, int XFP32>
__global__ __launch_bounds__(256) void gemm_mfma_sig_pool(
    const void* __restrict__ Wv, const float* __restrict__ bias,
    const void* __restrict__ Xv, void* __restrict__ Y,
    int K, int Np, int out_bf16) {
  __shared__ unsigned short Wt[64][GK_PADK];
  __shared__ unsigned short Xt[64][GK_PADK];
  const int tid = threadIdx.x;
  const int i_base = blockIdx.x * 64;
  const int b_base = blockIdx.y * 64;
  const int srow = tid >> 2, sseg = tid & 3;
  const int wv = tid >> 6, lane = tid & 63;
  const int wn = wv & 1, wb = wv >> 1;
  const int L15 = lane & 15, q = lane >> 4;

  f32x4 acc[2][2] = {};
  for (int k0 = 0; k0 < K; k0 += 32) {
    if (WFP32) {
      const float* Wf = (const float*)Wv;
      const float4 a = *(const float4*)&Wf[(size_t)(i_base + srow) * K + k0 + sseg * 8];
      const float4 b = *(const float4*)&Wf[(size_t)(i_base + srow) * K + k0 + sseg * 8 + 4];
      uint4 p = { pack2bf(a.x, a.y), pack2bf(a.z, a.w), pack2bf(b.x, b.y), pack2bf(b.z, b.w) };
      *(uint4*)&Wt[srow][sseg * 8] = p;
    } else {
      *(uint4*)&Wt[srow][sseg * 8] =
          *(const uint4*)&((const unsigned short*)Wv)[(size_t)(i_base + srow) * K + k0 + sseg * 8];
    }
    if (XFP32) {
      const float* Xf = (const float*)Xv;
      const float4 a = *(const float4*)&Xf[(size_t)(b_base + srow) * K + k0 + sseg * 8];
      const float4 b = *(const float4*)&Xf[(size_t)(b_base + srow) * K + k0 + sseg * 8 + 4];
      uint4 p = { pack2bf(a.x, a.y), pack2bf(a.z, a.w), pack2bf(b.x, b.y), pack2bf(b.z, b.w) };
      *(uint4*)&Xt[srow][sseg * 8] = p;
    } else {
      *(uint4*)&Xt[srow][sseg * 8] =
          *(const uint4*)&((const unsigned short*)Xv)[(size_t)(b_base + srow) * K + k0 + sseg * 8];
    }
    __syncthreads();
    bf16x8 a0 = *(const bf16x8*)&Wt[wn * 32 + L15][q * 8];
    bf16x8 a1 = *(const bf16x8*)&Wt[wn * 32 + 16 + L15][q * 8];
    bf16x8 b0 = *(const bf16x8*)&Xt[wb * 32 + L15][q * 8];
    bf16x8 b1 = *(const bf16x8*)&Xt[wb * 32 + 16 + L15][q * 8];
    acc[0][0] = __builtin_amdgcn_mfma_f32_16x16x32_bf16(a0, b0, acc[0][0], 0, 0, 0);
    acc[0][1] = __builtin_amdgcn_mfma_f32_16x16x32_bf16(a0, b1, acc[0][1], 0, 0, 0);
    acc[1][0] = __builtin_amdgcn_mfma_f32_16x16x32_bf16(a1, b0, acc[1][0], 0, 0, 0);
    acc[1][1] = __builtin_amdgcn_mfma_f32_16x16x32_bf16(a1, b1, acc[1][1], 0, 0, 0);
    __syncthreads();
  }

  const int nb0 = i_base + wn * 32;
  const int bc0 = b_base + wb * 32 + L15;
#pragma unroll
  for (int mg = 0; mg < 2; mg++) {
    const int nrow = nb0 + mg * 16 + q * 4;
    const float bi0 = bias[nrow], bi1 = bias[nrow + 1];
    const float bi2 = bias[nrow + 2], bi3 = bias[nrow + 3];
#pragma unroll
    for (int bg = 0; bg < 2; bg++) {
      const int b = bc0 + bg * 16;
      f32x4 A = acc[mg][bg];
      const float a0 = __builtin_amdgcn_rcpf(1.f + __expf(-(A[0] + bi0)));
      const float a1 = __builtin_amdgcn_rcpf(1.f + __expf(-(A[1] + bi1)));
      const float a2 = __builtin_amdgcn_rcpf(1.f + __expf(-(A[2] + bi2)));
      const float a3 = __builtin_amdgcn_rcpf(1.f + __expf(-(A[3] + bi3)));
      const float p0 = 0.5f * (a0 + a1), p1 = 0.5f * (a2 + a3);
      const int pidx = nrow >> 1;  // even
      if (out_bf16) {
        *(unsigned int*)&((unsigned short*)Y)[(size_t)b * Np + pidx] = pack2bf(p0, p1);
      } else {
        *(float2*)&((float*)Y)[(size_t)b * Np + pidx] = make_float2(p0, p1);
      }
    }
  }
}

// ---------- MFMA LSTM (R17): 4 waves, 1/SIMD, two-round quad-split act ----------
// R16 counters: VALUBusy 40% (=~520 cyc/step of issue; accvgpr-split + selects
// + act, x2 waves/SIMD), MFMA 300, rest latency/barrier. Fix: 256 thr -> one
// wave per SIMD (issue contention halved, barrier syncs 4 waves); single
// 3-chain MFMA acc per tile (no za/zb accvgpr storm); wave owns 6-7 of the 25
// tiles; activation in two rounds: lane c handles gate c&3 of wave-slot c>>2
// (round A, always active) and slot 4+(c>>2) (round B, masked) -- DPP quad
// structure intact per round, two cst registers. K-trim kept: k in [96,100) +
// bias + Wih*x in fp32 VALU tail.
#define TSTEPS 256

__device__ __forceinline__ float qb0(float x) {
  return __builtin_bit_cast(float, __builtin_amdgcn_mov_dpp(__builtin_bit_cast(int, x), 0x00, 0xf, 0xf, true));
}
__device__ __forceinline__ float qb1(float x) {
  return __builtin_bit_cast(float, __builtin_amdgcn_mov_dpp(__builtin_bit_cast(int, x), 0x55, 0xf, 0xf, true));
}
__device__ __forceinline__ float qb2(float x) {
  return __builtin_bit_cast(float, __builtin_amdgcn_mov_dpp(__builtin_bit_cast(int, x), 0xAA, 0xf, 0xf, true));
}
__device__ __forceinline__ float qb3(float x) {
  return __builtin_bit_cast(float, __builtin_amdgcn_mov_dpp(__builtin_bit_cast(int, x), 0xFF, 0xf, 0xf, true));
}

__global__ __launch_bounds__(256, 1) void lstm_mfma(
    const float* __restrict__ X, const _Float16* __restrict__ P,
    const float* __restrict__ Whh, const float* __restrict__ Wih,
    const float* __restrict__ b3, const float* __restrict__ Wout,
    const float* __restrict__ bout, float* __restrict__ out) {
  const int bat = blockIdx.x;
  const int t = threadIdx.x;
  const int w = t >> 6, lane = t & 63;
  const int quad = lane >> 4, c = lane & 15;
  const int TB = (w == 3) ? 18 : w * 6;   // w0:0-5 w1:6-11 w2:12-17 w3:18-24
  const int NT = (w == 3) ? 7 : 6;

  __shared__ __align__(16) _Float16 hbuf[2][128];
  __shared__ float xrow[TSTEPS];
  __shared__ float red[128];

  for (int i = t; i < TSTEPS; i += 256) xrow[i] = X[(size_t)bat * TSTEPS + i];
  ((_Float16*)hbuf)[t] = (_Float16)0.f;   // zero both buffers (256 halves)

  // A-fragments: slot J (perm rows 16(TB+J)+c), K-tile KT (k = 32KT + 8quad).
  // All row indices <= 399, loads unconditionally valid; slot 6 used only w==3.
#define LDA(J, KT) const f16x8 A##J##KT = \
    *(const f16x8*)&P[(size_t)((TB + J) * 16 + c) * 128 + (KT) * 32 + quad * 8];
  LDA(0,0) LDA(0,1) LDA(0,2)
  LDA(1,0) LDA(1,1) LDA(1,2)
  LDA(2,0) LDA(2,1) LDA(2,2)
  LDA(3,0) LDA(3,1) LDA(3,2)
  LDA(4,0) LDA(4,1) LDA(4,2)
  LDA(5,0) LDA(5,1) LDA(5,2)
  LDA(6,0) LDA(6,1) LDA(6,2)
#undef LDA

  // activation roles: round A slot sA = c>>2 (always < NT); round B slot sB = 4+(c>>2)
  const int g = c & 3, ssel = c >> 2;
  const int sB = 4 + ssel;
  const bool actB = (sB < NT);
  const int hidA = 4 * (TB + ssel) + quad;
  const int hidB = 4 * (TB + (actB ? sB : 0)) + quad;
  const int growA = g * 100 + hidA;
  const int growB = g * 100 + hidB;
  const float uA = Wih[growA], bzA = b3[growA];
  const float uB = Wih[growB], bzB = b3[growB];
  const float4 wtA = *(const float4*)&Whh[(size_t)growA * 100 + 96];
  const float4 wtB = *(const float4*)&Whh[(size_t)growB * 100 + 96];
  const float kk = (g == 2) ? 2.f : 1.f;   // g-gate: tanh = 2*sig(2z)-1
  const float mm = (g == 2) ? 2.f : 1.f;
  const float dd = (g == 2) ? -1.f : 0.f;
  float cstA = 0.f, cstB = 0.f;
  __syncthreads();

#define SIG(zz) __builtin_amdgcn_rcpf(1.f + __expf(-(zz)))
#define STEPB(HC, HN, XT)                                                      \
  {                                                                            \
    const _Float16* hc = (HC);                                                 \
    const f16x8 B0 = *(const f16x8*)&hc[0 * 32 + quad * 8];                    \
    const f16x8 B1 = *(const f16x8*)&hc[1 * 32 + quad * 8];                    \
    const f16x8 B2 = *(const f16x8*)&hc[2 * 32 + quad * 8];                    \
    f32x4 z0 = {0.f,0.f,0.f,0.f}, z1 = z0, z2 = z0, z3 = z0;                   \
    f32x4 z4 = z0, z5 = z0, z6 = z0;                                           \
    z0 = __builtin_amdgcn_mfma_f32_16x16x32_f16(A00, B0, z0, 0, 0, 0);         \
    z0 = __builtin_amdgcn_mfma_f32_16x16x32_f16(A01, B1, z0, 0, 0, 0);         \
    z0 = __builtin_amdgcn_mfma_f32_16x16x32_f16(A02, B2, z0, 0, 0, 0);         \
    z1 = __builtin_amdgcn_mfma_f32_16x16x32_f16(A10, B0, z1, 0, 0, 0);         \
    z1 = __builtin_amdgcn_mfma_f32_16x16x32_f16(A11, B1, z1, 0, 0, 0);         \
    z1 = __builtin_amdgcn_mfma_f32_16x16x32_f16(A12, B2, z1, 0, 0, 0);         \
    z2 = __builtin_amdgcn_mfma_f32_16x16x32_f16(A20, B0, z2, 0, 0, 0);         \
    z2 = __builtin_amdgcn_mfma_f32_16x16x32_f16(A21, B1, z2, 0, 0, 0);         \
    z2 = __builtin_amdgcn_mfma_f32_16x16x32_f16(A22, B2, z2, 0, 0, 0);         \
    z3 = __builtin_amdgcn_mfma_f32_16x16x32_f16(A30, B0, z3, 0, 0, 0);         \
    z3 = __builtin_amdgcn_mfma_f32_16x16x32_f16(A31, B1, z3, 0, 0, 0);         \
    z3 = __builtin_amdgcn_mfma_f32_16x16x32_f16(A32, B2, z3, 0, 0, 0);         \
    z4 = __builtin_amdgcn_mfma_f32_16x16x32_f16(A40, B0, z4, 0, 0, 0);         \
    z4 = __builtin_amdgcn_mfma_f32_16x16x32_f16(A41, B1, z4, 0, 0, 0);         \
    z4 = __builtin_amdgcn_mfma_f32_16x16x32_f16(A42, B2, z4, 0, 0, 0);         \
    z5 = __builtin_amdgcn_mfma_f32_16x16x32_f16(A50, B0, z5, 0, 0, 0);         \
    z5 = __builtin_amdgcn_mfma_f32_16x16x32_f16(A51, B1, z5, 0, 0, 0);         \
    z5 = __builtin_amdgcn_mfma_f32_16x16x32_f16(A52, B2, z5, 0, 0, 0);         \
    if (w == 3) {                                                              \
      z6 = __builtin_amdgcn_mfma_f32_16x16x32_f16(A60, B0, z6, 0, 0, 0);       \
      z6 = __builtin_amdgcn_mfma_f32_16x16x32_f16(A61, B1, z6, 0, 0, 0);       \
      z6 = __builtin_amdgcn_mfma_f32_16x16x32_f16(A62, B2, z6, 0, 0, 0);       \
    }                                                                          \
    const f16x4 htv = *(const f16x4*)&hc[96];                                  \
    const float h96 = (float)htv[0], h97 = (float)htv[1];                      \
    const float h98 = (float)htv[2], h99 = (float)htv[3];                      \
    const f32x4 ztA = (ssel == 0) ? z0 : (ssel == 1) ? z1 : (ssel == 2) ? z2 : z3; \
    const f32x4 ztB = (ssel == 0) ? z4 : (ssel == 1) ? z5 : z6;                \
    float zsA = (g == 0) ? ztA[0] : (g == 1) ? ztA[1] : (g == 2) ? ztA[2] : ztA[3]; \
    float zsB = (g == 0) ? ztB[0] : (g == 1) ? ztB[1] : (g == 2) ? ztB[2] : ztB[3]; \
    {                                                                          \
      float zz = zsA;                                                          \
      zz = fmaf(wtA.x, h96, zz); zz = fmaf(wtA.y, h97, zz);                    \
      zz = fmaf(wtA.z, h98, zz); zz = fmaf(wtA.w, h99, zz);                    \
      zz = fmaf(uA, (XT), zz + bzA);                                           \
      const float a = mm * SIG(kk * zz) + dd;                                  \
      const float ai = qb0(a), af = qb1(a), ag2 = qb2(a), ao = qb3(a);         \
      cstA = fmaf(af, cstA, ai * ag2);                                         \
      const float th = 2.f * SIG(2.f * cstA) - 1.f;                            \
      if (g == 0) (HN)[hidA] = (_Float16)(ao * th);                            \
    }                                                                          \
    {                                                                          \
      float zz = zsB;                                                          \
      zz = fmaf(wtB.x, h96, zz); zz = fmaf(wtB.y, h97, zz);                    \
      zz = fmaf(wtB.z, h98, zz); zz = fmaf(wtB.w, h99, zz);                    \
      zz = fmaf(uB, (XT), zz + bzB);                                           \
      const float a = mm * SIG(kk * zz) + dd;                                  \
      const float ai = qb0(a), af = qb1(a), ag2 = qb2(a), ao = qb3(a);         \
      cstB = fmaf(af, cstB, ai * ag2);                                         \
      const float th = 2.f * SIG(2.f * cstB) - 1.f;                            \
      if (actB && g == 0) (HN)[hidB] = (_Float16)(ao * th);                    \
    }                                                                          \
    __syncthreads();                                                           \
  }

  for (int step = 0; step < TSTEPS; step += 2) {
    STEPB(hbuf[0], hbuf[1], xrow[step]);
    STEPB(hbuf[1], hbuf[0], xrow[step + 1]);
  }
#undef STEPB
#undef SIG

  // out[bat] = dot(h_final, Wout) + bout; final h in hbuf[0]
  if (t < 128) {
    float a = 0.f;
    if (t < 100) a = (float)hbuf[0][t] * Wout[t];
    red[t] = a;
  }
  __syncthreads();
  if (t == 0) {
    float s = 0.f;
#pragma unroll
    for (int k = 0; k < 128; k++) s += red[k];
    out[bat] = s + bout[0];
  }
}

// ---------- launch ----------
extern "C" void kernel_launch(void* const* d_in, const int* in_sizes, int n_in,
                              void* d_out, int out_size, void* d_ws, size_t ws_size,
                              hipStream_t stream) {
  const float* x    = (const float*)d_in[0];   // (256,1024)
  const float* W1L  = (const float*)d_in[3];   // (1024,1024)
  const float* b1L  = (const float*)d_in[4];
  const float* W2L  = (const float*)d_in[7];   // (512,512)
  const float* b2L  = (const float*)d_in[8];
  const float* Wih3 = (const float*)d_in[15];  // (400,1)
  const float* Whh3 = (const float*)d_in[16];  // (400,100)
  const float* b3   = (const float*)d_in[17];  // (400,)
  const float* Wout = (const float*)d_in[18];  // (1,100)
  const float* bout = (const float*)d_in[19];  // (1,)
  float* out = (float*)d_out;                  // (256,)

  unsigned short* W1Lb = (unsigned short*)d_ws;        // 1048576 ushorts
  unsigned short* W2Lb = W1Lb + 1048576;               // 262144
  unsigned short* xb   = W2Lb + 262144;                // 262144
  unsigned short* xl1b = xb + 262144;                  // 131072 (256x512 bf16)
  float* xl2 = (float*)(xl1b + 131072);                // 65536 floats (256x256)
  _Float16* P = (_Float16*)(xl2 + 65536);              // 400x128 fp16

  convert_prep<<<1561, 256, 0, stream>>>(W1L, W2L, x, W1Lb, W2Lb, xb,
                                         1048576, 262144, 262144, Whh3, P);
  gemm_mfma_sig_pool<0, 0><<<dim3(16, 4), 256, 0, stream>>>(W1Lb, b1L, xb, xl1b, 1024, 512, 1);
  gemm_mfma_sig_pool<0, 0><<<dim3(8, 4), 256, 0, stream>>>(W2Lb, b2L, xl1b, xl2, 512, 256, 0);
  lstm_mfma<<<256, 256, 0, stream>>>(xl2, P, Whh3, Wih3, b3, Wout, bout, out);
}